// Round 1
// baseline (47.976 us; speedup 1.0000x reference)
//
#include <hip/hip_runtime.h>

typedef __bf16 bf16x8 __attribute__((ext_vector_type(8)));
typedef float f32x4 __attribute__((ext_vector_type(4)));
typedef unsigned short ushort8 __attribute__((ext_vector_type(8)));

#define D 128
#define TILE 128

static __device__ __forceinline__ unsigned short f32_to_bf16(float f) {
  unsigned int u = __float_as_uint(f);
  u += 0x7fffu + ((u >> 16) & 1u);   // RNE
  return (unsigned short)(u >> 16);
}

// One block = 16 rows, 16 lanes per row. Normalizes both matrices to bf16 in ws,
// and accumulates the diagonal correction sum_i (1 - cos_ii - relu(cos_ii)).
__global__ void normalize_diag_kernel(const float* __restrict__ anc,
                                      const float* __restrict__ pos,
                                      unsigned short* __restrict__ wsA,
                                      unsigned short* __restrict__ wsP,
                                      float* __restrict__ diag_acc) {
  __shared__ float rowc[16];
  const int t = threadIdx.x;
  const int rl = t >> 4, l16 = t & 15;
  const int row = blockIdx.x * 16 + rl;
  const float* ar = anc + (size_t)row * D + l16 * 8;
  const float* pr = pos + (size_t)row * D + l16 * 8;
  float4 a0 = *(const float4*)ar, a1 = *(const float4*)(ar + 4);
  float4 p0 = *(const float4*)pr, p1 = *(const float4*)(pr + 4);
  float av[8] = {a0.x, a0.y, a0.z, a0.w, a1.x, a1.y, a1.z, a1.w};
  float pv[8] = {p0.x, p0.y, p0.z, p0.w, p1.x, p1.y, p1.z, p1.w};
  float ssa = 0.f, ssp = 0.f;
#pragma unroll
  for (int k = 0; k < 8; ++k) { ssa += av[k] * av[k]; ssp += pv[k] * pv[k]; }
#pragma unroll
  for (int off = 1; off < 16; off <<= 1) {
    ssa += __shfl_xor(ssa, off);
    ssp += __shfl_xor(ssp, off);
  }
  const float sa = 1.f / fmaxf(sqrtf(ssa), 1e-8f);
  const float sp = 1.f / fmaxf(sqrtf(ssp), 1e-8f);
  float dot = 0.f;
  ushort8 a8, p8;
#pragma unroll
  for (int k = 0; k < 8; ++k) {
    const float an = av[k] * sa, pn = pv[k] * sp;
    dot += an * pn;
    a8[k] = f32_to_bf16(an);
    p8[k] = f32_to_bf16(pn);
  }
  *(ushort8*)(wsA + (size_t)row * D + l16 * 8) = a8;
  *(ushort8*)(wsP + (size_t)row * D + l16 * 8) = p8;
#pragma unroll
  for (int off = 1; off < 16; off <<= 1) dot += __shfl_xor(dot, off);
  if (l16 == 0) rowc[rl] = 1.f - dot - fmaxf(dot, 0.f);
  __syncthreads();
  if (t == 0) {
    float s = 0.f;
#pragma unroll
    for (int i = 0; i < 16; ++i) s += rowc[i];
    atomicAdd(diag_acc, s);
  }
}

// 128x128 tile per block, 4 waves each computing a 64x64 subtile via 4x4
// mfma_f32_16x16x32_bf16 fragments. Full K=128 staged once via global_load_lds
// (16B) with XOR swizzle pre-applied on the GLOBAL source (linear LDS dest),
// so swizzled ds_read_b128 fragment reads are bank-conflict-free.
__global__ __launch_bounds__(256, 2) void gemm_relu_sum_kernel(
    const unsigned short* __restrict__ wsA,
    const unsigned short* __restrict__ wsP,
    float* __restrict__ partials) {
  __shared__ __align__(16) unsigned short ldsA[TILE * D];
  __shared__ __align__(16) unsigned short ldsP[TILE * D];
  __shared__ float wpart[4];
  const int tid = threadIdx.x;
  const int w = tid >> 6, l = tid & 63;

  const char* gA = (const char*)(wsA + (size_t)blockIdx.x * TILE * D);
  const char* gP = (const char*)(wsP + (size_t)blockIdx.y * TILE * D);
  char* lA = (char*)ldsA;
  char* lP = (char*)ldsP;
#pragma unroll
  for (int it = 0; it < 8; ++it) {
    const int g = it * 256 + w * 64 + l;     // 16B chunk index 0..2047
    const int row = g >> 4, slot = g & 15;   // row 0..127, 16B slot 0..15
    const int src = slot ^ (row & 7);        // pre-swizzled global source
    const int goff = row * 256 + src * 16;
    const int lbase = (it * 256 + w * 64) * 16;  // wave-uniform LDS base
    __builtin_amdgcn_global_load_lds(
        (const __attribute__((address_space(1))) char*)(gA + goff),
        (__attribute__((address_space(3))) char*)(lA + lbase), 16, 0, 0);
    __builtin_amdgcn_global_load_lds(
        (const __attribute__((address_space(1))) char*)(gP + goff),
        (__attribute__((address_space(3))) char*)(lP + lbase), 16, 0, 0);
  }
  __syncthreads();

  f32x4 acc[4][4] = {};
  const int wr = (w >> 1) * 64, wc = (w & 1) * 64;
  const int r16 = l & 15, kg = l >> 4;
#pragma unroll
  for (int ks = 0; ks < 4; ++ks) {
    bf16x8 af[4], bfr[4];
    const int slot = ks * 4 + kg;   // 16B k-slot within the 256B row
#pragma unroll
    for (int m = 0; m < 4; ++m) {
      const int r = wr + m * 16 + r16;
      af[m] = *(const bf16x8*)(lA + r * 256 + ((slot ^ (r & 7)) * 16));
    }
#pragma unroll
    for (int n = 0; n < 4; ++n) {
      const int r = wc + n * 16 + r16;
      bfr[n] = *(const bf16x8*)(lP + r * 256 + ((slot ^ (r & 7)) * 16));
    }
#pragma unroll
    for (int m = 0; m < 4; ++m)
#pragma unroll
      for (int n = 0; n < 4; ++n)
        acc[m][n] = __builtin_amdgcn_mfma_f32_16x16x32_bf16(af[m], bfr[n],
                                                            acc[m][n], 0, 0, 0);
  }

  // relu-sum of everything this wave computed (layout-oblivious reduction)
  float s = 0.f;
#pragma unroll
  for (int m = 0; m < 4; ++m)
#pragma unroll
    for (int n = 0; n < 4; ++n)
#pragma unroll
      for (int q = 0; q < 4; ++q) s += fmaxf(acc[m][n][q], 0.f);
#pragma unroll
  for (int off = 32; off >= 1; off >>= 1) s += __shfl_xor(s, off);
  if (l == 0) wpart[w] = s;
  __syncthreads();
  if (tid == 0)
    partials[blockIdx.y * gridDim.x + blockIdx.x] =
        wpart[0] + wpart[1] + wpart[2] + wpart[3];
}

__global__ void finalize_kernel(const float* __restrict__ partials,
                                const float* __restrict__ diag_acc,
                                float* __restrict__ out, int nPart, float invBB) {
  __shared__ float wsum[4];
  const int t = threadIdx.x;
  float s = 0.f;
  for (int i = t; i < nPart; i += 256) s += partials[i];
#pragma unroll
  for (int off = 32; off >= 1; off >>= 1) s += __shfl_xor(s, off);
  if ((t & 63) == 0) wsum[t >> 6] = s;
  __syncthreads();
  if (t == 0) out[0] = (wsum[0] + wsum[1] + wsum[2] + wsum[3] + *diag_acc) * invBB;
}

extern "C" void kernel_launch(void* const* d_in, const int* in_sizes, int n_in,
                              void* d_out, int out_size, void* d_ws, size_t ws_size,
                              hipStream_t stream) {
  const float* pos = (const float*)d_in[0];  // hid_positive
  const float* anc = (const float*)d_in[1];  // hid_anchor
  const int B = in_sizes[0] / D;             // 8192

  char* ws = (char*)d_ws;
  unsigned short* wsA = (unsigned short*)ws;                         // B*D bf16
  unsigned short* wsP = (unsigned short*)(ws + (size_t)B * D * 2);   // B*D bf16
  float* partials = (float*)(ws + (size_t)B * D * 4);
  const int nbm = B / TILE;
  const int nPart = nbm * nbm;
  float* diag_acc = partials + nPart;

  hipMemsetAsync(diag_acc, 0, sizeof(float), stream);
  normalize_diag_kernel<<<B / 16, 256, 0, stream>>>(anc, pos, wsA, wsP, diag_acc);
  gemm_relu_sum_kernel<<<dim3(nbm, nbm), 256, 0, stream>>>(wsA, wsP, partials);
  const float invBB = 1.0f / ((float)B * (float)B);
  finalize_kernel<<<1, 256, 0, stream>>>(partials, diag_acc, (float*)d_out, nPart, invBB);
}

// Round 2
// 34.192 us; speedup vs baseline: 1.4031x; 1.4031x over previous
//
#include <hip/hip_runtime.h>

typedef __bf16 bf16x8 __attribute__((ext_vector_type(8)));
typedef float f32x4 __attribute__((ext_vector_type(4)));
typedef unsigned short ushort8 __attribute__((ext_vector_type(8)));

#define D 128
#define TILE 256   // 256x256 output tile per block

static __device__ __forceinline__ unsigned short f32_to_bf16(float f) {
  unsigned int u = __float_as_uint(f);
  u += 0x7fffu + ((u >> 16) & 1u);   // RNE
  return (unsigned short)(u >> 16);
}

// One block = 16 rows, 16 lanes per row. Normalizes both matrices to bf16 in ws
// and writes this block's diagonal correction sum_i (1 - cos_ii - relu(cos_ii))
// to diagP[blockIdx.x]  (deterministic, no atomics, no zero-init needed).
__global__ void normalize_diag_kernel(const float* __restrict__ anc,
                                      const float* __restrict__ pos,
                                      unsigned short* __restrict__ wsA,
                                      unsigned short* __restrict__ wsP,
                                      float* __restrict__ diagP) {
  __shared__ float rowc[16];
  const int t = threadIdx.x;
  const int rl = t >> 4, l16 = t & 15;
  const int row = blockIdx.x * 16 + rl;
  const float* ar = anc + (size_t)row * D + l16 * 8;
  const float* pr = pos + (size_t)row * D + l16 * 8;
  float4 a0 = *(const float4*)ar, a1 = *(const float4*)(ar + 4);
  float4 p0 = *(const float4*)pr, p1 = *(const float4*)(pr + 4);
  float av[8] = {a0.x, a0.y, a0.z, a0.w, a1.x, a1.y, a1.z, a1.w};
  float pv[8] = {p0.x, p0.y, p0.z, p0.w, p1.x, p1.y, p1.z, p1.w};
  float ssa = 0.f, ssp = 0.f;
#pragma unroll
  for (int k = 0; k < 8; ++k) { ssa += av[k] * av[k]; ssp += pv[k] * pv[k]; }
#pragma unroll
  for (int off = 1; off < 16; off <<= 1) {
    ssa += __shfl_xor(ssa, off);
    ssp += __shfl_xor(ssp, off);
  }
  const float sa = 1.f / fmaxf(sqrtf(ssa), 1e-8f);
  const float sp = 1.f / fmaxf(sqrtf(ssp), 1e-8f);
  float dot = 0.f;
  ushort8 a8, p8;
#pragma unroll
  for (int k = 0; k < 8; ++k) {
    const float an = av[k] * sa, pn = pv[k] * sp;
    dot += an * pn;
    a8[k] = f32_to_bf16(an);
    p8[k] = f32_to_bf16(pn);
  }
  *(ushort8*)(wsA + (size_t)row * D + l16 * 8) = a8;
  *(ushort8*)(wsP + (size_t)row * D + l16 * 8) = p8;
#pragma unroll
  for (int off = 1; off < 16; off <<= 1) dot += __shfl_xor(dot, off);
  if (l16 == 0) rowc[rl] = 1.f - dot - fmaxf(dot, 0.f);
  __syncthreads();
  if (t == 0) {
    float s = 0.f;
#pragma unroll
    for (int i = 0; i < 16; ++i) s += rowc[i];
    diagP[blockIdx.x] = s;
  }
}

// 256x256 tile per block, 8 waves (2x4), each computing a 128x64 subtile via
// 8x4 mfma_f32_16x16x32_bf16 fragments. Full K=128 staged once via
// global_load_lds (16B) with XOR swizzle pre-applied on the GLOBAL source
// (linear LDS dest, rule #21), so swizzled ds_read_b128 reads are
// bank-conflict-free. Epilogue: relu-sum (layout-oblivious).
__global__ __launch_bounds__(512, 2) void gemm_relu_sum_kernel(
    const unsigned short* __restrict__ wsA,
    const unsigned short* __restrict__ wsP,
    float* __restrict__ partials) {
  __shared__ __align__(16) unsigned short ldsA[TILE * D];
  __shared__ __align__(16) unsigned short ldsP[TILE * D];
  __shared__ float wpart[8];
  const int tid = threadIdx.x;
  const int w = tid >> 6, l = tid & 63;

  const char* gA = (const char*)(wsA + (size_t)blockIdx.x * TILE * D);
  const char* gP = (const char*)(wsP + (size_t)blockIdx.y * TILE * D);
  char* lA = (char*)ldsA;
  char* lP = (char*)ldsP;
#pragma unroll
  for (int it = 0; it < 8; ++it) {
    const int g = it * 512 + w * 64 + l;     // 16B chunk index 0..4095
    const int row = g >> 4, slot = g & 15;   // row 0..255, slot 0..15
    const int src = slot ^ (row & 7);        // pre-swizzled global source
    const int goff = row * 256 + src * 16;
    const int lbase = (it * 512 + w * 64) * 16;  // wave-uniform LDS base
    __builtin_amdgcn_global_load_lds(
        (const __attribute__((address_space(1))) char*)(gA + goff),
        (__attribute__((address_space(3))) char*)(lA + lbase), 16, 0, 0);
    __builtin_amdgcn_global_load_lds(
        (const __attribute__((address_space(1))) char*)(gP + goff),
        (__attribute__((address_space(3))) char*)(lP + lbase), 16, 0, 0);
  }
  __syncthreads();

  f32x4 acc[8][4] = {};
  const int wr = (w >> 2) * 128, wc = (w & 3) * 64;   // wave subtile origin
  const int r16 = l & 15, kg = l >> 4;
#pragma unroll
  for (int ks = 0; ks < 4; ++ks) {
    bf16x8 af[8], bfr[4];
    const int slot = ks * 4 + kg;   // 16B k-slot within the 256B row
#pragma unroll
    for (int m = 0; m < 8; ++m) {
      const int r = wr + m * 16 + r16;
      af[m] = *(const bf16x8*)(lA + r * 256 + ((slot ^ (r & 7)) * 16));
    }
#pragma unroll
    for (int n = 0; n < 4; ++n) {
      const int r = wc + n * 16 + r16;
      bfr[n] = *(const bf16x8*)(lP + r * 256 + ((slot ^ (r & 7)) * 16));
    }
#pragma unroll
    for (int m = 0; m < 8; ++m)
#pragma unroll
      for (int n = 0; n < 4; ++n)
        acc[m][n] = __builtin_amdgcn_mfma_f32_16x16x32_bf16(af[m], bfr[n],
                                                            acc[m][n], 0, 0, 0);
  }

  // relu-sum of everything this wave computed (layout-oblivious)
  float s = 0.f;
#pragma unroll
  for (int m = 0; m < 8; ++m)
#pragma unroll
    for (int n = 0; n < 4; ++n)
#pragma unroll
      for (int q = 0; q < 4; ++q) s += fmaxf(acc[m][n][q], 0.f);
#pragma unroll
  for (int off = 32; off >= 1; off >>= 1) s += __shfl_xor(s, off);
  if (l == 0) wpart[w] = s;
  __syncthreads();
  if (tid == 0) {
    float b = 0.f;
#pragma unroll
    for (int i = 0; i < 8; ++i) b += wpart[i];
    partials[blockIdx.y * gridDim.x + blockIdx.x] = b;
  }
}

__global__ void finalize_kernel(const float* __restrict__ partials, int nPart,
                                const float* __restrict__ diagP, int nDiag,
                                float* __restrict__ out, float invBB) {
  __shared__ float wsum[4];
  const int t = threadIdx.x;
  float s = 0.f;
  for (int i = t; i < nPart; i += 256) s += partials[i];
  for (int i = t; i < nDiag; i += 256) s += diagP[i];
#pragma unroll
  for (int off = 32; off >= 1; off >>= 1) s += __shfl_xor(s, off);
  if ((t & 63) == 0) wsum[t >> 6] = s;
  __syncthreads();
  if (t == 0) out[0] = (wsum[0] + wsum[1] + wsum[2] + wsum[3]) * invBB;
}

extern "C" void kernel_launch(void* const* d_in, const int* in_sizes, int n_in,
                              void* d_out, int out_size, void* d_ws, size_t ws_size,
                              hipStream_t stream) {
  const float* pos = (const float*)d_in[0];  // hid_positive
  const float* anc = (const float*)d_in[1];  // hid_anchor
  const int B = in_sizes[0] / D;             // 8192

  char* ws = (char*)d_ws;
  unsigned short* wsA = (unsigned short*)ws;                         // B*D bf16
  unsigned short* wsP = (unsigned short*)(ws + (size_t)B * D * 2);   // B*D bf16
  float* partials = (float*)(ws + (size_t)B * D * 4);
  const int nbm = B / TILE;                  // 32
  const int nPart = nbm * nbm;               // 1024
  float* diagP = partials + nPart;
  const int nDiag = B / 16;                  // 512

  normalize_diag_kernel<<<nDiag, 256, 0, stream>>>(anc, pos, wsA, wsP, diagP);
  gemm_relu_sum_kernel<<<dim3(nbm, nbm), 512, 0, stream>>>(wsA, wsP, partials);
  const float invBB = 1.0f / ((float)B * (float)B);
  finalize_kernel<<<1, 256, 0, stream>>>(partials, nPart, diagP, nDiag,
                                         (float*)d_out, invBB);
}